// Round 10
// baseline (178.926 us; speedup 1.0000x reference)
//
#include <hip/hip_runtime.h>
#include <stdint.h>
#include <stddef.h>

#define DIM 256
#define NB 16
#define HH 56
#define WW 56
#define HWP (HH*WW)          // 3136
#define PH 62
#define PW 62
#define NPIX (NB*HWP)        // 50176
#define EPSV 1e-5f

using f32x4  = __attribute__((ext_vector_type(4))) float;
using bf16x8 = __attribute__((ext_vector_type(8))) __bf16;

static __device__ __forceinline__ unsigned short f2bf(float f) {
    union { float f; unsigned u; } v; v.f = f;
    unsigned r = v.u + 0x7FFFu + ((v.u >> 16) & 1u);
    return (unsigned short)(r >> 16);
}
static __device__ __forceinline__ float bf2f(unsigned short u) {
    union { unsigned u; float f; } v; v.u = ((unsigned)u) << 16; return v.f;
}
static __device__ __forceinline__ float silu_f(float z) {
    return z / (1.f + __expf(-z));
}

// ---------------- P1: fold BN into weights, merge 1x1 into 3x3 center, merge depthwise ----
__global__ void prep_weights(
    const float* __restrict__ w3, const float* __restrict__ g1, const float* __restrict__ b1,
    const float* __restrict__ m1, const float* __restrict__ v1, const float* __restrict__ w1,
    const float* __restrict__ g2, const float* __restrict__ b2, const float* __restrict__ m2,
    const float* __restrict__ v2, const float* __restrict__ dw7, const float* __restrict__ dwk,
    const float* __restrict__ g3, const float* __restrict__ b3, const float* __restrict__ m3,
    const float* __restrict__ v3,
    unsigned short* __restrict__ WkT, float* __restrict__ dwm, float* __restrict__ biasm,
    float* __restrict__ sc3, float* __restrict__ bi3)
{
    int co = blockIdx.x, t = threadIdx.x;          // t = ci
    float s1 = g1[co] * rsqrtf(v1[co] + EPSV);
    float s2 = g2[co] * rsqrtf(v2[co] + EPSV);
    float w1v = w1[co*DIM + t] * s2;
    const float* w3r = w3 + (size_t)(co*DIM + t)*9;
#pragma unroll
    for (int s = 0; s < 9; ++s) {
        float v = w3r[s]*s1 + (s == 4 ? w1v : 0.f);
        WkT[((size_t)s*DIM + co)*DIM + t] = f2bf(v);   // layout [tap][co][ci]
    }
    if (t < 49) dwm[co*49 + t] = dw7[co*49 + t] + dwk[co*49 + t];
    if (t == 0) {
        biasm[co] = (b1[co] - m1[co]*s1) + (b2[co] - m2[co]*s2);
        float s3 = g3[co] * rsqrtf(v3[co] + EPSV);
        sc3[co] = s3;
        bi3[co] = b3[co] - m3[co]*s3;
    }
}

// ---------------- P2: x NCHW f32 -> padded NHWC bf16 (writes its own halo zeros) --------
__global__ void prep_xpad(const float* __restrict__ x, unsigned short* __restrict__ xpad)
{
    __shared__ float lds[64][57];
    int cc = blockIdx.x;      // 0..3 channel chunk of 64
    int ph = blockIdx.y;      // 0..61 padded row
    int b  = blockIdx.z;      // 0..15
    int t  = threadIdx.x;
    int c0 = cc*64;
    char* rowc = (char*)xpad + ((size_t)(b*PH + ph)*PW)*(DIM*2) + c0*2;

    if (ph < 3 || ph >= HH + 3) {
        uint4 z = {0u,0u,0u,0u};
#pragma unroll
        for (int j = 0; j < 2; ++j) {
            int idx = j*256 + t;
            if (idx < 496) {
                int pix = idx >> 3, q = idx & 7;
                *(uint4*)(rowc + (size_t)pix*(DIM*2) + q*16) = z;
            }
        }
        return;
    }
    if (t < 48) {
        int p = t >> 3, q = t & 7;
        int pw = (p < 3) ? p : (PW - 6 + p);       // 0,1,2, 59,60,61
        uint4 z = {0u,0u,0u,0u};
        *(uint4*)(rowc + (size_t)pw*(DIM*2) + q*16) = z;
    }
    int h = ph - 3;
#pragma unroll
    for (int j = 0; j < 14; ++j) {                   // 64*56 = 3584 = 14*256
        int idx = j*256 + t;
        int c = idx / 56, w = idx % 56;
        lds[c][w] = x[((size_t)(b*DIM + c0 + c)*HH + h)*WW + w];
    }
    __syncthreads();
#pragma unroll
    for (int j = 0; j < 7; ++j) {                    // 56*32 pairs = 1792 = 7*256
        int idx = j*256 + t;
        int w = idx >> 5, cp = idx & 31;
        unsigned lo = f2bf(lds[2*cp][w]);
        unsigned hi = f2bf(lds[2*cp+1][w]);
        unsigned val = lo | (hi << 16);
        *(unsigned*)(rowc + (size_t)(w + 3)*(DIM*2) + 4*cp) = val;
    }
}

// ---------------- P3: merged depthwise 7x7, vectorized LDS reads, 8-wide strips --------
__global__ void depthwise7(const float* __restrict__ x, const float* __restrict__ dwm,
                           unsigned short* __restrict__ dwout)
{
    __shared__ float plane[PH][64];                  // rows padded to 64 (16B-aligned vec reads)
    int c = blockIdx.x, b = blockIdx.y, t = threadIdx.x;
#pragma unroll
    for (int j = 0; j < 4; ++j) {
        int idx = j*256 + t;
        if (idx < 992) ((f32x4*)plane)[idx] = (f32x4){0.f,0.f,0.f,0.f};
    }
    __syncthreads();
    const float* xp = x + ((size_t)b*DIM + c)*HWP;
#pragma unroll
    for (int j = 0; j < 13; ++j) {
        int idx = j*256 + t;
        if (idx < HWP) {
            int h = idx / 56, w = idx % 56;
            plane[h + 3][w + 3] = xp[idx];
        }
    }
    float wr[49];
#pragma unroll
    for (int i = 0; i < 49; ++i) wr[i] = dwm[c*49 + i];   // uniform -> SGPR
    __syncthreads();
    unsigned short* op = dwout + ((size_t)b*DIM + c)*HWP;
#pragma unroll
    for (int j = 0; j < 2; ++j) {                    // 392 octs = 56 rows x 7
        int q = j*256 + t;
        if (q < 392) {
            int h = q / 7, w0 = (q % 7)*8;
            float a[8] = {0.f,0.f,0.f,0.f,0.f,0.f,0.f,0.f};
#pragma unroll
            for (int dy = 0; dy < 7; ++dy) {
                const float* row = &plane[h + dy][w0];
                union { f32x4 v[4]; float s[16]; } rr;
                rr.v[0] = *(const f32x4*)(row);
                rr.v[1] = *(const f32x4*)(row + 4);
                rr.v[2] = *(const f32x4*)(row + 8);
                rr.v[3] = *(const f32x4*)(row + 12);
#pragma unroll
                for (int dx = 0; dx < 7; ++dx) {
                    float wv = wr[dy*7 + dx];
#pragma unroll
                    for (int o = 0; o < 8; ++o) a[o] += rr.s[dx + o] * wv;
                }
            }
            uint4 pk;
            pk.x = (unsigned)f2bf(a[0]) | ((unsigned)f2bf(a[1]) << 16);
            pk.y = (unsigned)f2bf(a[2]) | ((unsigned)f2bf(a[3]) << 16);
            pk.z = (unsigned)f2bf(a[4]) | ((unsigned)f2bf(a[5]) << 16);
            pk.w = (unsigned)f2bf(a[6]) | ((unsigned)f2bf(a[7]) << 16);
            *(uint4*)&op[h*WW + w0] = pk;
        }
    }
}

// ---------------- Main: implicit-GEMM conv3x3, 128x128 tile, BK=32, 4 blocks/CU --------
// Diagnosis R2..R9: latency-bound (all pipes <25%, occupancy 15%) at 2 blocks/CU.
// Fix: BK=32 -> LDS 32KB/block -> 4 blocks/CU (16 waves) for TLP, with the validated
// 16x16x32 compute + R2 epilogue + counted vmcnt(4) (never 0 in steady state) loop.
// 72 K-tiles; per K-tile: stage A 8KB + B 8KB (2+2 loads/thread), 8 b128 frag reads,
// 16 MFMA/wave. Rows are 64B (4 chunks); swizzle chunk^(row&3) via pre-swizzled source.
__global__ __launch_bounds__(256, 4)
void main_conv(const unsigned short* __restrict__ xpad, const unsigned short* __restrict__ WkT,
               const unsigned short* __restrict__ dwo, const float* __restrict__ biasm,
               const float* __restrict__ sc3, const float* __restrict__ bi3,
               float* __restrict__ out)
{
    __shared__ __align__(16) char smem[32768];       // buf{0,1}: A 8K + B 8K
    int t = threadIdx.x;
    int lane = t & 63, wv = t >> 6;
    int wm = wv >> 1, wn = wv & 1;
    int qm = lane & 15, qg = lane >> 4;
    int bx = blockIdx.x;

    // staging: thread t covers rows p*64 + (t>>2) (p=0,1), chunk t&3 (16B of a 64B row)
    int swz = (((t & 3) ^ ((t >> 2) & 3)) << 4);     // pre-swizzled source chunk

    uintptr_t gA[2], gB[2];
#pragma unroll
    for (int p = 0; p < 2; ++p) {
        int row = p*64 + (t >> 2);
        int P = bx*128 + row;
        int bb = P / HWP, rem = P % HWP;
        int h = rem / WW, w = rem % WW;
        gA[p] = (uintptr_t)xpad + ((size_t)((bb*PH + h + 2)*PW + (w + 2))*DIM)*2 + swz;
        int cog = blockIdx.y*128 + row;
        gB[p] = (uintptr_t)WkT + ((size_t)cog*DIM)*2 + swz;
    }

    f32x4 acc[4][4] = {};

    // kt = 0..71: tap = kt>>3, ci_base = (kt&7)*32
    auto stage = [&](int kt, int buf) {
        int tap = kt >> 3, cb = kt & 7;
        int ky = tap / 3, kx = tap - ky*3;
        int offA = (ky*PW + kx)*(DIM*2) + cb*64;
        int offB = tap*(DIM*DIM*2) + cb*64;
        char* base = smem + buf*16384;
#pragma unroll
        for (int p = 0; p < 2; ++p)
            __builtin_amdgcn_global_load_lds(
                (const __attribute__((address_space(1))) void*)(gA[p] + offA),
                (__attribute__((address_space(3))) void*)(base + p*4096 + t*16),
                16, 0, 0);
#pragma unroll
        for (int p = 0; p < 2; ++p)
            __builtin_amdgcn_global_load_lds(
                (const __attribute__((address_space(1))) void*)(gB[p] + offB),
                (__attribute__((address_space(3))) void*)(base + 8192 + p*4096 + t*16),
                16, 0, 0);
    };

    int ko = ((qg ^ (qm & 3)) << 4);                 // phys chunk = qg ^ (row&3)
    auto compute = [&](int buf) {
        const char* pA = smem + buf*16384 + (wm*64 + qm)*64 + ko;
        const char* pB = smem + buf*16384 + 8192 + (wn*64 + qm)*64 + ko;
        bf16x8 a[4], b[4];
#pragma unroll
        for (int i = 0; i < 4; ++i) {
            a[i] = *(const bf16x8*)(pA + i*1024);
            b[i] = *(const bf16x8*)(pB + i*1024);
        }
        __builtin_amdgcn_s_setprio(1);
#pragma unroll
        for (int i = 0; i < 4; ++i)
#pragma unroll
            for (int j = 0; j < 4; ++j)
                acc[i][j] = __builtin_amdgcn_mfma_f32_16x16x32_bf16(a[i], b[j], acc[i][j], 0, 0, 0);
        __builtin_amdgcn_s_setprio(0);
    };

#define VMW4() asm volatile("s_waitcnt vmcnt(4)" ::: "memory")
#define VMW0() asm volatile("s_waitcnt vmcnt(0)" ::: "memory")
#define BARX() { asm volatile("" ::: "memory"); __builtin_amdgcn_s_barrier(); asm volatile("" ::: "memory"); }

    stage(0, 0);
    stage(1, 1);
    VMW4(); BARX();                       // stage(0) landed & published
#pragma unroll 1
    for (int s = 0; s < 72; ++s) {
        compute(s & 1);                   // stage(s+1) flying underneath
        BARX();                           // all waves done reading buf (s&1)
        if (s <= 69) {
            stage(s + 2, s & 1);          // refill the buffer just freed
            VMW4();                       // stage(s+1) landed (4 newest = stage(s+2))
            BARX();                       // publish
        } else if (s == 70) {
            VMW0();                       // drain stage(71) for the last step
            BARX();
        }
    }
#undef VMW4
#undef VMW0
#undef BARX

    // ---- epilogue: R2-proven transpose through LDS (per-wave disjoint, fully unrolled) ----
    float* ep = (float*)smem + wv*1088;               // 64 co x 16 pix, stride 17
#pragma unroll
    for (int mi = 0; mi < 4; ++mi) {
#pragma unroll
        for (int ni = 0; ni < 4; ++ni)
#pragma unroll
            for (int r = 0; r < 4; ++r)
                ep[(ni*16 + qm)*17 + 4*qg + r] = acc[mi][ni][r];
        asm volatile("s_waitcnt lgkmcnt(0)" ::: "memory");
        __builtin_amdgcn_sched_barrier(0);
        int P = bx*128 + wm*64 + mi*16 + qm;          // this lane's pixel
        int bb = P / HWP, rem = P % HWP;
        size_t obase = (size_t)bb*DIM*HWP + rem;
#pragma unroll
        for (int j = 0; j < 16; ++j) {
            int col = j*4 + qg;                       // 0..63 within wave's co range
            int cog = blockIdx.y*128 + wn*64 + col;
            float z = ep[col*17 + qm] + biasm[cog];
            float rep = silu_f(z);
            float y = rep + bf2f(dwo[obase + (size_t)cog*HWP]);
            float yy = y * sc3[cog] + bi3[cog];
            out[obase + (size_t)cog*HWP] = silu_f(yy);
        }
        asm volatile("s_waitcnt lgkmcnt(0)" ::: "memory");
        __builtin_amdgcn_sched_barrier(0);
    }
}

// ---------------- launch ----------------
extern "C" void kernel_launch(void* const* d_in, const int* in_sizes, int n_in,
                              void* d_out, int out_size, void* d_ws, size_t ws_size,
                              hipStream_t stream)
{
    (void)in_sizes; (void)n_in; (void)out_size; (void)ws_size;
    const float* x   = (const float*)d_in[0];
    const float* w3  = (const float*)d_in[1];
    const float* g1  = (const float*)d_in[2];
    const float* b1  = (const float*)d_in[3];
    const float* m1  = (const float*)d_in[4];
    const float* v1  = (const float*)d_in[5];
    const float* w1  = (const float*)d_in[6];
    const float* g2  = (const float*)d_in[7];
    const float* b2  = (const float*)d_in[8];
    const float* m2  = (const float*)d_in[9];
    const float* v2  = (const float*)d_in[10];
    const float* dw7 = (const float*)d_in[11];
    const float* dwk = (const float*)d_in[12];
    const float* g3  = (const float*)d_in[13];
    const float* b3  = (const float*)d_in[14];
    const float* m3  = (const float*)d_in[15];
    const float* v3  = (const float*)d_in[16];
    float* out = (float*)d_out;

    char* ws = (char*)d_ws;
    unsigned short* xpad = (unsigned short*)(ws);                 // 16*62*62*256*2 = 31,490,048
    unsigned short* WkT  = (unsigned short*)(ws + 31490048);      // 9*256*256*2    =  1,179,648
    unsigned short* dwo  = (unsigned short*)(ws + 32669696);      // 16*256*3136*2  = 25,690,112
    float* dwm   = (float*)(ws + 58359808);                       // 256*49*4
    float* biasm = (float*)(ws + 58409984);
    float* sc3   = (float*)(ws + 58411008);
    float* bi3   = (float*)(ws + 58412032);                       // end ~58.4 MB

    prep_weights<<<dim3(DIM), dim3(256), 0, stream>>>(
        w3, g1, b1, m1, v1, w1, g2, b2, m2, v2, dw7, dwk, g3, b3, m3, v3,
        WkT, dwm, biasm, sc3, bi3);
    prep_xpad<<<dim3(4, PH, NB), dim3(256), 0, stream>>>(x, xpad);
    depthwise7<<<dim3(DIM, NB), dim3(256), 0, stream>>>(x, dwm, dwo);
    main_conv<<<dim3(NPIX/128, 2), dim3(256), 0, stream>>>(xpad, WkT, dwo, biasm, sc3, bi3, out);
}

// Round 11
// 146.508 us; speedup vs baseline: 1.2213x; 1.2213x over previous
//
#include <hip/hip_runtime.h>
#include <stdint.h>
#include <stddef.h>

#define DIM 256
#define NB 16
#define HH 56
#define WW 56
#define HWP (HH*WW)          // 3136
#define PH 62
#define PW 62
#define NPIX (NB*HWP)        // 50176
#define EPSV 1e-5f

using f32x4  = __attribute__((ext_vector_type(4))) float;
using bf16x8 = __attribute__((ext_vector_type(8))) __bf16;

static __device__ __forceinline__ unsigned short f2bf(float f) {
    union { float f; unsigned u; } v; v.f = f;
    unsigned r = v.u + 0x7FFFu + ((v.u >> 16) & 1u);
    return (unsigned short)(r >> 16);
}
static __device__ __forceinline__ float bf2f(unsigned short u) {
    union { unsigned u; float f; } v; v.u = ((unsigned)u) << 16; return v.f;
}
static __device__ __forceinline__ float silu_f(float z) {
    return z / (1.f + __expf(-z));
}

// ---------------- P1: fold BN into weights, merge 1x1 into 3x3 center, merge depthwise ----
__global__ void prep_weights(
    const float* __restrict__ w3, const float* __restrict__ g1, const float* __restrict__ b1,
    const float* __restrict__ m1, const float* __restrict__ v1, const float* __restrict__ w1,
    const float* __restrict__ g2, const float* __restrict__ b2, const float* __restrict__ m2,
    const float* __restrict__ v2, const float* __restrict__ dw7, const float* __restrict__ dwk,
    const float* __restrict__ g3, const float* __restrict__ b3, const float* __restrict__ m3,
    const float* __restrict__ v3,
    unsigned short* __restrict__ WkT, float* __restrict__ dwm, float* __restrict__ biasm,
    float* __restrict__ sc3, float* __restrict__ bi3)
{
    int co = blockIdx.x, t = threadIdx.x;          // t = ci
    float s1 = g1[co] * rsqrtf(v1[co] + EPSV);
    float s2 = g2[co] * rsqrtf(v2[co] + EPSV);
    float w1v = w1[co*DIM + t] * s2;
    const float* w3r = w3 + (size_t)(co*DIM + t)*9;
#pragma unroll
    for (int s = 0; s < 9; ++s) {
        float v = w3r[s]*s1 + (s == 4 ? w1v : 0.f);
        WkT[((size_t)s*DIM + co)*DIM + t] = f2bf(v);   // layout [tap][co][ci]
    }
    if (t < 49) dwm[co*49 + t] = dw7[co*49 + t] + dwk[co*49 + t];
    if (t == 0) {
        biasm[co] = (b1[co] - m1[co]*s1) + (b2[co] - m2[co]*s2);
        float s3 = g3[co] * rsqrtf(v3[co] + EPSV);
        sc3[co] = s3;
        bi3[co] = b3[co] - m3[co]*s3;
    }
}

// ---------------- P2: x NCHW f32 -> padded NHWC bf16 (writes its own halo zeros) --------
__global__ void prep_xpad(const float* __restrict__ x, unsigned short* __restrict__ xpad)
{
    __shared__ float lds[64][57];
    int cc = blockIdx.x;      // 0..3 channel chunk of 64
    int ph = blockIdx.y;      // 0..61 padded row
    int b  = blockIdx.z;      // 0..15
    int t  = threadIdx.x;
    int c0 = cc*64;
    char* rowc = (char*)xpad + ((size_t)(b*PH + ph)*PW)*(DIM*2) + c0*2;

    if (ph < 3 || ph >= HH + 3) {
        uint4 z = {0u,0u,0u,0u};
#pragma unroll
        for (int j = 0; j < 2; ++j) {
            int idx = j*256 + t;
            if (idx < 496) {
                int pix = idx >> 3, q = idx & 7;
                *(uint4*)(rowc + (size_t)pix*(DIM*2) + q*16) = z;
            }
        }
        return;
    }
    if (t < 48) {
        int p = t >> 3, q = t & 7;
        int pw = (p < 3) ? p : (PW - 6 + p);       // 0,1,2, 59,60,61
        uint4 z = {0u,0u,0u,0u};
        *(uint4*)(rowc + (size_t)pw*(DIM*2) + q*16) = z;
    }
    int h = ph - 3;
#pragma unroll
    for (int j = 0; j < 14; ++j) {                   // 64*56 = 3584 = 14*256
        int idx = j*256 + t;
        int c = idx / 56, w = idx % 56;
        lds[c][w] = x[((size_t)(b*DIM + c0 + c)*HH + h)*WW + w];
    }
    __syncthreads();
#pragma unroll
    for (int j = 0; j < 7; ++j) {                    // 56*32 pairs = 1792 = 7*256
        int idx = j*256 + t;
        int w = idx >> 5, cp = idx & 31;
        unsigned lo = f2bf(lds[2*cp][w]);
        unsigned hi = f2bf(lds[2*cp+1][w]);
        unsigned val = lo | (hi << 16);
        *(unsigned*)(rowc + (size_t)(w + 3)*(DIM*2) + 4*cp) = val;
    }
}

// ---------------- P3: merged depthwise 7x7, vectorized LDS reads, 8-wide strips --------
__global__ void depthwise7(const float* __restrict__ x, const float* __restrict__ dwm,
                           unsigned short* __restrict__ dwout)
{
    __shared__ float plane[PH][64];                  // rows padded to 64 (16B-aligned vec reads)
    int c = blockIdx.x, b = blockIdx.y, t = threadIdx.x;
#pragma unroll
    for (int j = 0; j < 4; ++j) {
        int idx = j*256 + t;
        if (idx < 992) ((f32x4*)plane)[idx] = (f32x4){0.f,0.f,0.f,0.f};
    }
    __syncthreads();
    const float* xp = x + ((size_t)b*DIM + c)*HWP;
#pragma unroll
    for (int j = 0; j < 13; ++j) {
        int idx = j*256 + t;
        if (idx < HWP) {
            int h = idx / 56, w = idx % 56;
            plane[h + 3][w + 3] = xp[idx];
        }
    }
    float wr[49];
#pragma unroll
    for (int i = 0; i < 49; ++i) wr[i] = dwm[c*49 + i];   // uniform -> SGPR
    __syncthreads();
    unsigned short* op = dwout + ((size_t)b*DIM + c)*HWP;
#pragma unroll
    for (int j = 0; j < 2; ++j) {                    // 392 octs = 56 rows x 7
        int q = j*256 + t;
        if (q < 392) {
            int h = q / 7, w0 = (q % 7)*8;
            float a[8] = {0.f,0.f,0.f,0.f,0.f,0.f,0.f,0.f};
#pragma unroll
            for (int dy = 0; dy < 7; ++dy) {
                const float* row = &plane[h + dy][w0];
                union { f32x4 v[4]; float s[16]; } rr;
                rr.v[0] = *(const f32x4*)(row);
                rr.v[1] = *(const f32x4*)(row + 4);
                rr.v[2] = *(const f32x4*)(row + 8);
                rr.v[3] = *(const f32x4*)(row + 12);
#pragma unroll
                for (int dx = 0; dx < 7; ++dx) {
                    float wv = wr[dy*7 + dx];
#pragma unroll
                    for (int o = 0; o < 8; ++o) a[o] += rr.s[dx + o] * wv;
                }
            }
            uint4 pk;
            pk.x = (unsigned)f2bf(a[0]) | ((unsigned)f2bf(a[1]) << 16);
            pk.y = (unsigned)f2bf(a[2]) | ((unsigned)f2bf(a[3]) << 16);
            pk.z = (unsigned)f2bf(a[4]) | ((unsigned)f2bf(a[5]) << 16);
            pk.w = (unsigned)f2bf(a[6]) | ((unsigned)f2bf(a[7]) << 16);
            *(uint4*)&op[h*WW + w0] = pk;
        }
    }
}

// ---------------- Main: implicit-GEMM conv3x3 (R2-validated structure) + L2 locality ---
// Byte-exact R2 pipeline (128x128 tile, BK=64, dbuf, 1 __syncthreads/K-step) with:
// (1) K-order flipped to TAP-INNER / CHANNEL-OUTER: tap = kt%9, ch = kt/9 -> the same
//     16KB A-chunk is re-read for 9 consecutive K-steps (~80KB live set, L2-resident)
//     so A staging loads are L2-hits whose latency hides under compute.
// (2) grid (2, 392): the two co-tiles sharing an A-tile are dispatch-adjacent (same XCD).
__global__ __launch_bounds__(256, 2)
void main_conv(const unsigned short* __restrict__ xpad, const unsigned short* __restrict__ WkT,
               const unsigned short* __restrict__ dwo, const float* __restrict__ biasm,
               const float* __restrict__ sc3, const float* __restrict__ bi3,
               float* __restrict__ out)
{
    __shared__ __align__(16) char smem[65536];       // buf0: A 16K + B 16K, buf1: same
    int t = threadIdx.x;
    int lane = t & 63, wv = t >> 6;
    int wm = wv >> 1, wn = wv & 1;
    int qm = lane & 15, qg = lane >> 4;
    int bx = blockIdx.y;                              // pixel tile (392)
    int byc = blockIdx.x;                             // co tile (2)

    // staging: lane covers row (r*32 + wv*8 + lane/8), 16B chunk (lane&7), XOR-swizzled source
    int swz = (((lane & 7) ^ ((lane >> 3) & 7)) << 4);

    uintptr_t gA[4], gB[4];
#pragma unroll
    for (int r = 0; r < 4; ++r) {
        int pixt = r*32 + wv*8 + (lane >> 3);
        int P = bx*128 + pixt;
        int bb = P / HWP, rem = P % HWP;
        int h = rem / WW, w = rem % WW;
        gA[r] = (uintptr_t)xpad + ((size_t)((bb*PH + h + 2)*PW + (w + 2))*DIM)*2 + swz;
        int cog = byc*128 + pixt;
        gB[r] = (uintptr_t)WkT + ((size_t)cog*DIM)*2 + swz;
    }

    f32x4 acc[4][4] = {};

    auto stage = [&](int s, int buf) {
        int ch = s / 9, tap = s - ch*9;               // TAP-INNER, CHANNEL-OUTER
        int ky = tap / 3, kx = tap - ky*3;
        int offA = (ky*PW + kx)*(DIM*2) + ch*128;
        int offB = tap*(DIM*DIM*2) + ch*128;
        char* base = smem + buf*32768;
#pragma unroll
        for (int r = 0; r < 4; ++r) {
            __builtin_amdgcn_global_load_lds(
                (const __attribute__((address_space(1))) void*)(gA[r] + offA),
                (__attribute__((address_space(3))) void*)(base + (r*32 + wv*8)*128),
                16, 0, 0);
            __builtin_amdgcn_global_load_lds(
                (const __attribute__((address_space(1))) void*)(gB[r] + offB),
                (__attribute__((address_space(3))) void*)(base + 16384 + (r*32 + wv*8)*128),
                16, 0, 0);
        }
    };

    int kxo = (qg << 4) ^ ((lane & 7) << 4);
    auto compute = [&](int buf) {
        const char* pA = smem + buf*32768 + (wm*64 + qm)*128;
        const char* pB = smem + buf*32768 + 16384 + (wn*64 + qm)*128;
#pragma unroll
        for (int kk = 0; kk < 2; ++kk) {
            int ko = kxo ^ (kk << 6);
            bf16x8 a[4], b[4];
#pragma unroll
            for (int i = 0; i < 4; ++i) {
                a[i] = *(const bf16x8*)(pA + i*2048 + ko);
                b[i] = *(const bf16x8*)(pB + i*2048 + ko);
            }
#pragma unroll
            for (int i = 0; i < 4; ++i)
#pragma unroll
                for (int j = 0; j < 4; ++j)
                    acc[i][j] = __builtin_amdgcn_mfma_f32_16x16x32_bf16(a[i], b[j], acc[i][j], 0, 0, 0);
        }
    };

    stage(0, 0);
    __syncthreads();
#pragma unroll 1
    for (int it = 0; it < 18; ++it) {
        stage(2*it + 1, 1);          // prefetch odd step into buf1 (flies under compute)
        compute(0);                  // consume even step from buf0
        __syncthreads();             // drains vmcnt(0): buf1 ready; buf0 free
        if (it < 17) stage(2*it + 2, 0);
        compute(1);
        __syncthreads();
    }

    // ---- epilogue: per-wave transpose through LDS -> coalesced NCHW stores ----
    float* ep = (float*)smem + wv*1088;               // 64 co x 16 pix, stride 17
#pragma unroll
    for (int mi = 0; mi < 4; ++mi) {
#pragma unroll
        for (int ni = 0; ni < 4; ++ni)
#pragma unroll
            for (int r = 0; r < 4; ++r)
                ep[(ni*16 + qm)*17 + 4*qg + r] = acc[mi][ni][r];
        __syncthreads();
        int P = bx*128 + wm*64 + mi*16 + qm;          // this lane's pixel
        int bb = P / HWP, rem = P % HWP;
        size_t obase = (size_t)bb*DIM*HWP + rem;
#pragma unroll
        for (int j = 0; j < 16; ++j) {
            int col = j*4 + qg;                       // 0..63 within wave's co range
            int cog = byc*128 + wn*64 + col;
            float z = ep[col*17 + qm] + biasm[cog];
            float rep = silu_f(z);
            float y = rep + bf2f(dwo[obase + (size_t)cog*HWP]);
            float yy = y * sc3[cog] + bi3[cog];
            out[obase + (size_t)cog*HWP] = silu_f(yy);
        }
        __syncthreads();
    }
}

// ---------------- launch ----------------
extern "C" void kernel_launch(void* const* d_in, const int* in_sizes, int n_in,
                              void* d_out, int out_size, void* d_ws, size_t ws_size,
                              hipStream_t stream)
{
    (void)in_sizes; (void)n_in; (void)out_size; (void)ws_size;
    const float* x   = (const float*)d_in[0];
    const float* w3  = (const float*)d_in[1];
    const float* g1  = (const float*)d_in[2];
    const float* b1  = (const float*)d_in[3];
    const float* m1  = (const float*)d_in[4];
    const float* v1  = (const float*)d_in[5];
    const float* w1  = (const float*)d_in[6];
    const float* g2  = (const float*)d_in[7];
    const float* b2  = (const float*)d_in[8];
    const float* m2  = (const float*)d_in[9];
    const float* v2  = (const float*)d_in[10];
    const float* dw7 = (const float*)d_in[11];
    const float* dwk = (const float*)d_in[12];
    const float* g3  = (const float*)d_in[13];
    const float* b3  = (const float*)d_in[14];
    const float* m3  = (const float*)d_in[15];
    const float* v3  = (const float*)d_in[16];
    float* out = (float*)d_out;

    char* ws = (char*)d_ws;
    unsigned short* xpad = (unsigned short*)(ws);                 // 16*62*62*256*2 = 31,490,048
    unsigned short* WkT  = (unsigned short*)(ws + 31490048);      // 9*256*256*2    =  1,179,648
    unsigned short* dwo  = (unsigned short*)(ws + 32669696);      // 16*256*3136*2  = 25,690,112
    float* dwm   = (float*)(ws + 58359808);                       // 256*49*4
    float* biasm = (float*)(ws + 58409984);
    float* sc3   = (float*)(ws + 58411008);
    float* bi3   = (float*)(ws + 58412032);                       // end ~58.4 MB

    prep_weights<<<dim3(DIM), dim3(256), 0, stream>>>(
        w3, g1, b1, m1, v1, w1, g2, b2, m2, v2, dw7, dwk, g3, b3, m3, v3,
        WkT, dwm, biasm, sc3, bi3);
    prep_xpad<<<dim3(4, PH, NB), dim3(256), 0, stream>>>(x, xpad);
    depthwise7<<<dim3(DIM, NB), dim3(256), 0, stream>>>(x, dwm, dwo);
    main_conv<<<dim3(2, NPIX/128), dim3(256), 0, stream>>>(xpad, WkT, dwo, biasm, sc3, bi3, out);
}

// Round 12
// 143.514 us; speedup vs baseline: 1.2467x; 1.0209x over previous
//
#include <hip/hip_runtime.h>
#include <stdint.h>
#include <stddef.h>

#define DIM 256
#define NB 16
#define HH 56
#define WW 56
#define HWP (HH*WW)          // 3136
#define PH 62
#define PW 62
#define NPIX (NB*HWP)        // 50176
#define EPSV 1e-5f

using f32x4  = __attribute__((ext_vector_type(4))) float;
using bf16x8 = __attribute__((ext_vector_type(8))) __bf16;

static __device__ __forceinline__ unsigned short f2bf(float f) {
    union { float f; unsigned u; } v; v.f = f;
    unsigned r = v.u + 0x7FFFu + ((v.u >> 16) & 1u);
    return (unsigned short)(r >> 16);
}
static __device__ __forceinline__ float bf2f(unsigned short u) {
    union { unsigned u; float f; } v; v.u = ((unsigned)u) << 16; return v.f;
}
static __device__ __forceinline__ float silu_f(float z) {
    return z / (1.f + __expf(-z));
}

// ---------------- Fused prep: depthwise7 (blocks 0..4095), xpad (4096..8063),
//                  weights (8064..8319) — independent work, one launch ----------------
// P1: fold BN into 3x3 (+1x1 center), merge depthwise weights, fold final BN.
// P2: x NCHW f32 -> padded NHWC bf16 (writes its own halo zeros).
// P3: merged depthwise 7x7 per (b,c) plane via LDS, bf16 NCHW out.
__global__ __launch_bounds__(256)
void fused_prep(const float* __restrict__ x,
                const float* __restrict__ w3, const float* __restrict__ g1,
                const float* __restrict__ b1, const float* __restrict__ m1,
                const float* __restrict__ v1, const float* __restrict__ w1,
                const float* __restrict__ g2, const float* __restrict__ b2,
                const float* __restrict__ m2, const float* __restrict__ v2,
                const float* __restrict__ dw7, const float* __restrict__ dwk,
                const float* __restrict__ g3, const float* __restrict__ b3,
                const float* __restrict__ m3, const float* __restrict__ v3,
                unsigned short* __restrict__ xpad, unsigned short* __restrict__ WkT,
                unsigned short* __restrict__ dwout, float* __restrict__ biasm,
                float* __restrict__ sc3, float* __restrict__ bi3)
{
    __shared__ float shbuf[PH*64];                   // P3: plane[62][64]; P2: lds[64][57]
    int bid = blockIdx.x;
    int t = threadIdx.x;

    if (bid < 4096) {
        // ---------------- P3: depthwise 7x7, c = bid&255, b = bid>>8 ----------------
        float (*plane)[64] = (float(*)[64])shbuf;
        int c = bid & 255, b = bid >> 8;
#pragma unroll
        for (int j = 0; j < 4; ++j) {
            int idx = j*256 + t;
            if (idx < 992) ((f32x4*)plane)[idx] = (f32x4){0.f,0.f,0.f,0.f};
        }
        __syncthreads();
        const float* xp = x + ((size_t)b*DIM + c)*HWP;
#pragma unroll
        for (int j = 0; j < 13; ++j) {
            int idx = j*256 + t;
            if (idx < HWP) {
                int h = idx / 56, w = idx % 56;
                plane[h + 3][w + 3] = xp[idx];
            }
        }
        float wr[49];
#pragma unroll
        for (int i = 0; i < 49; ++i) wr[i] = dw7[c*49 + i] + dwk[c*49 + i];  // uniform -> SGPR
        __syncthreads();
        unsigned short* op = dwout + ((size_t)b*DIM + c)*HWP;
#pragma unroll
        for (int j = 0; j < 2; ++j) {                // 392 octs = 56 rows x 7
            int q = j*256 + t;
            if (q < 392) {
                int h = q / 7, w0 = (q % 7)*8;
                float a[8] = {0.f,0.f,0.f,0.f,0.f,0.f,0.f,0.f};
#pragma unroll
                for (int dy = 0; dy < 7; ++dy) {
                    const float* row = &plane[h + dy][w0];
                    union { f32x4 v[4]; float s[16]; } rr;
                    rr.v[0] = *(const f32x4*)(row);
                    rr.v[1] = *(const f32x4*)(row + 4);
                    rr.v[2] = *(const f32x4*)(row + 8);
                    rr.v[3] = *(const f32x4*)(row + 12);
#pragma unroll
                    for (int dx = 0; dx < 7; ++dx) {
                        float wv = wr[dy*7 + dx];
#pragma unroll
                        for (int o = 0; o < 8; ++o) a[o] += rr.s[dx + o] * wv;
                    }
                }
                uint4 pk;
                pk.x = (unsigned)f2bf(a[0]) | ((unsigned)f2bf(a[1]) << 16);
                pk.y = (unsigned)f2bf(a[2]) | ((unsigned)f2bf(a[3]) << 16);
                pk.z = (unsigned)f2bf(a[4]) | ((unsigned)f2bf(a[5]) << 16);
                pk.w = (unsigned)f2bf(a[6]) | ((unsigned)f2bf(a[7]) << 16);
                *(uint4*)&op[h*WW + w0] = pk;
            }
        }
        return;
    }

    if (bid < 8064) {
        // ---------------- P2: xpad, idx -> (cc, ph, b) ----------------
        float (*lds)[57] = (float(*)[57])shbuf;
        int idx0 = bid - 4096;
        int cc = idx0 & 3;                           // channel chunk of 64
        int r62 = (idx0 >> 2);
        int ph = r62 % PH, b = r62 / PH;
        int c0 = cc*64;
        char* rowc = (char*)xpad + ((size_t)(b*PH + ph)*PW)*(DIM*2) + c0*2;

        if (ph < 3 || ph >= HH + 3) {
            uint4 z = {0u,0u,0u,0u};
#pragma unroll
            for (int j = 0; j < 2; ++j) {
                int idx = j*256 + t;
                if (idx < 496) {
                    int pix = idx >> 3, q = idx & 7;
                    *(uint4*)(rowc + (size_t)pix*(DIM*2) + q*16) = z;
                }
            }
            return;
        }
        if (t < 48) {
            int p = t >> 3, q = t & 7;
            int pw = (p < 3) ? p : (PW - 6 + p);     // 0,1,2, 59,60,61
            uint4 z = {0u,0u,0u,0u};
            *(uint4*)(rowc + (size_t)pw*(DIM*2) + q*16) = z;
        }
        int h = ph - 3;
#pragma unroll
        for (int j = 0; j < 14; ++j) {               // 64*56 = 3584 = 14*256
            int idx = j*256 + t;
            int c = idx / 56, w = idx % 56;
            lds[c][w] = x[((size_t)(b*DIM + c0 + c)*HH + h)*WW + w];
        }
        __syncthreads();
#pragma unroll
        for (int j = 0; j < 7; ++j) {                // 56*32 pairs = 1792 = 7*256
            int idx = j*256 + t;
            int w = idx >> 5, cp = idx & 31;
            unsigned lo = f2bf(lds[2*cp][w]);
            unsigned hi = f2bf(lds[2*cp+1][w]);
            unsigned val = lo | (hi << 16);
            *(unsigned*)(rowc + (size_t)(w + 3)*(DIM*2) + 4*cp) = val;
        }
        return;
    }

    // ---------------- P1: weights, co = bid - 8064, t = ci ----------------
    {
        int co = bid - 8064;
        float s1 = g1[co] * rsqrtf(v1[co] + EPSV);
        float s2 = g2[co] * rsqrtf(v2[co] + EPSV);
        float w1v = w1[co*DIM + t] * s2;
        const float* w3r = w3 + (size_t)(co*DIM + t)*9;
#pragma unroll
        for (int s = 0; s < 9; ++s) {
            float v = w3r[s]*s1 + (s == 4 ? w1v : 0.f);
            WkT[((size_t)s*DIM + co)*DIM + t] = f2bf(v);   // layout [tap][co][ci]
        }
        if (t == 0) {
            biasm[co] = (b1[co] - m1[co]*s1) + (b2[co] - m2[co]*s2);
            float s3 = g3[co] * rsqrtf(v3[co] + EPSV);
            sc3[co] = s3;
            bi3[co] = b3[co] - m3[co]*s3;
        }
    }
}

// ---------------- Main: implicit-GEMM conv3x3 (R11-validated, unchanged) --------------
// 128x128 tile, BK=64, dbuf, tap-inner/channel-outer K-order (A chunk L2-resident for 9
// consecutive steps), grid (2 co, 392 px) so co-pairs sharing A are dispatch-adjacent.
__global__ __launch_bounds__(256, 2)
void main_conv(const unsigned short* __restrict__ xpad, const unsigned short* __restrict__ WkT,
               const unsigned short* __restrict__ dwo, const float* __restrict__ biasm,
               const float* __restrict__ sc3, const float* __restrict__ bi3,
               float* __restrict__ out)
{
    __shared__ __align__(16) char smem[65536];       // buf0: A 16K + B 16K, buf1: same
    int t = threadIdx.x;
    int lane = t & 63, wv = t >> 6;
    int wm = wv >> 1, wn = wv & 1;
    int qm = lane & 15, qg = lane >> 4;
    int bx = blockIdx.y;                              // pixel tile (392)
    int byc = blockIdx.x;                             // co tile (2)

    int swz = (((lane & 7) ^ ((lane >> 3) & 7)) << 4);

    uintptr_t gA[4], gB[4];
#pragma unroll
    for (int r = 0; r < 4; ++r) {
        int pixt = r*32 + wv*8 + (lane >> 3);
        int P = bx*128 + pixt;
        int bb = P / HWP, rem = P % HWP;
        int h = rem / WW, w = rem % WW;
        gA[r] = (uintptr_t)xpad + ((size_t)((bb*PH + h + 2)*PW + (w + 2))*DIM)*2 + swz;
        int cog = byc*128 + pixt;
        gB[r] = (uintptr_t)WkT + ((size_t)cog*DIM)*2 + swz;
    }

    f32x4 acc[4][4] = {};

    auto stage = [&](int s, int buf) {
        int ch = s / 9, tap = s - ch*9;               // TAP-INNER, CHANNEL-OUTER
        int ky = tap / 3, kx = tap - ky*3;
        int offA = (ky*PW + kx)*(DIM*2) + ch*128;
        int offB = tap*(DIM*DIM*2) + ch*128;
        char* base = smem + buf*32768;
#pragma unroll
        for (int r = 0; r < 4; ++r) {
            __builtin_amdgcn_global_load_lds(
                (const __attribute__((address_space(1))) void*)(gA[r] + offA),
                (__attribute__((address_space(3))) void*)(base + (r*32 + wv*8)*128),
                16, 0, 0);
            __builtin_amdgcn_global_load_lds(
                (const __attribute__((address_space(1))) void*)(gB[r] + offB),
                (__attribute__((address_space(3))) void*)(base + 16384 + (r*32 + wv*8)*128),
                16, 0, 0);
        }
    };

    int kxo = (qg << 4) ^ ((lane & 7) << 4);
    auto compute = [&](int buf) {
        const char* pA = smem + buf*32768 + (wm*64 + qm)*128;
        const char* pB = smem + buf*32768 + 16384 + (wn*64 + qm)*128;
#pragma unroll
        for (int kk = 0; kk < 2; ++kk) {
            int ko = kxo ^ (kk << 6);
            bf16x8 a[4], b[4];
#pragma unroll
            for (int i = 0; i < 4; ++i) {
                a[i] = *(const bf16x8*)(pA + i*2048 + ko);
                b[i] = *(const bf16x8*)(pB + i*2048 + ko);
            }
#pragma unroll
            for (int i = 0; i < 4; ++i)
#pragma unroll
                for (int j = 0; j < 4; ++j)
                    acc[i][j] = __builtin_amdgcn_mfma_f32_16x16x32_bf16(a[i], b[j], acc[i][j], 0, 0, 0);
        }
    };

    stage(0, 0);
    __syncthreads();
#pragma unroll 1
    for (int it = 0; it < 18; ++it) {
        stage(2*it + 1, 1);          // prefetch odd step into buf1 (flies under compute)
        compute(0);                  // consume even step from buf0
        __syncthreads();             // drains vmcnt(0): buf1 ready; buf0 free
        if (it < 17) stage(2*it + 2, 0);
        compute(1);
        __syncthreads();
    }

    // ---- epilogue: per-wave transpose through LDS -> coalesced NCHW stores ----
    float* ep = (float*)smem + wv*1088;               // 64 co x 16 pix, stride 17
#pragma unroll
    for (int mi = 0; mi < 4; ++mi) {
#pragma unroll
        for (int ni = 0; ni < 4; ++ni)
#pragma unroll
            for (int r = 0; r < 4; ++r)
                ep[(ni*16 + qm)*17 + 4*qg + r] = acc[mi][ni][r];
        __syncthreads();
        int P = bx*128 + wm*64 + mi*16 + qm;          // this lane's pixel
        int bb = P / HWP, rem = P % HWP;
        size_t obase = (size_t)bb*DIM*HWP + rem;
#pragma unroll
        for (int j = 0; j < 16; ++j) {
            int col = j*4 + qg;                       // 0..63 within wave's co range
            int cog = byc*128 + wn*64 + col;
            float z = ep[col*17 + qm] + biasm[cog];
            float rep = silu_f(z);
            float y = rep + bf2f(dwo[obase + (size_t)cog*HWP]);
            float yy = y * sc3[cog] + bi3[cog];
            out[obase + (size_t)cog*HWP] = silu_f(yy);
        }
        __syncthreads();
    }
}

// ---------------- launch ----------------
extern "C" void kernel_launch(void* const* d_in, const int* in_sizes, int n_in,
                              void* d_out, int out_size, void* d_ws, size_t ws_size,
                              hipStream_t stream)
{
    (void)in_sizes; (void)n_in; (void)out_size; (void)ws_size;
    const float* x   = (const float*)d_in[0];
    const float* w3  = (const float*)d_in[1];
    const float* g1  = (const float*)d_in[2];
    const float* b1  = (const float*)d_in[3];
    const float* m1  = (const float*)d_in[4];
    const float* v1  = (const float*)d_in[5];
    const float* w1  = (const float*)d_in[6];
    const float* g2  = (const float*)d_in[7];
    const float* b2  = (const float*)d_in[8];
    const float* m2  = (const float*)d_in[9];
    const float* v2  = (const float*)d_in[10];
    const float* dw7 = (const float*)d_in[11];
    const float* dwk = (const float*)d_in[12];
    const float* g3  = (const float*)d_in[13];
    const float* b3  = (const float*)d_in[14];
    const float* m3  = (const float*)d_in[15];
    const float* v3  = (const float*)d_in[16];
    float* out = (float*)d_out;

    char* ws = (char*)d_ws;
    unsigned short* xpad = (unsigned short*)(ws);                 // 16*62*62*256*2 = 31,490,048
    unsigned short* WkT  = (unsigned short*)(ws + 31490048);      // 9*256*256*2    =  1,179,648
    unsigned short* dwo  = (unsigned short*)(ws + 32669696);      // 16*256*3136*2  = 25,690,112
    float* biasm = (float*)(ws + 58359808);
    float* sc3   = (float*)(ws + 58360832);
    float* bi3   = (float*)(ws + 58361856);                       // end ~58.4 MB

    fused_prep<<<dim3(8320), dim3(256), 0, stream>>>(
        x, w3, g1, b1, m1, v1, w1, g2, b2, m2, v2, dw7, dwk, g3, b3, m3, v3,
        xpad, WkT, dwo, biasm, sc3, bi3);
    main_conv<<<dim3(2, NPIX/128), dim3(256), 0, stream>>>(xpad, WkT, dwo, biasm, sc3, bi3, out);
}

// Round 13
// 137.044 us; speedup vs baseline: 1.3056x; 1.0472x over previous
//
#include <hip/hip_runtime.h>
#include <stdint.h>
#include <stddef.h>

#define DIM 256
#define NB 16
#define HH 56
#define WW 56
#define HWP (HH*WW)          // 3136
#define PH 62
#define PW 62
#define NPIX (NB*HWP)        // 50176
#define EPSV 1e-5f

using f32x4  = __attribute__((ext_vector_type(4))) float;
using bf16x8 = __attribute__((ext_vector_type(8))) __bf16;

static __device__ __forceinline__ unsigned short f2bf(float f) {
    union { float f; unsigned u; } v; v.f = f;
    unsigned r = v.u + 0x7FFFu + ((v.u >> 16) & 1u);
    return (unsigned short)(r >> 16);
}
static __device__ __forceinline__ float bf2f(unsigned short u) {
    union { unsigned u; float f; } v; v.u = ((unsigned)u) << 16; return v.f;
}
static __device__ __forceinline__ float silu_f(float z) {
    return z / (1.f + __expf(-z));
}

// ---------------- Fused prep: depthwise7 (blocks 0..4095), xpad (4096..8063),
//                  weights (8064..8319) — independent work, one launch ----------------
__global__ __launch_bounds__(256)
void fused_prep(const float* __restrict__ x,
                const float* __restrict__ w3, const float* __restrict__ g1,
                const float* __restrict__ b1, const float* __restrict__ m1,
                const float* __restrict__ v1, const float* __restrict__ w1,
                const float* __restrict__ g2, const float* __restrict__ b2,
                const float* __restrict__ m2, const float* __restrict__ v2,
                const float* __restrict__ dw7, const float* __restrict__ dwk,
                const float* __restrict__ g3, const float* __restrict__ b3,
                const float* __restrict__ m3, const float* __restrict__ v3,
                unsigned short* __restrict__ xpad, unsigned short* __restrict__ WkT,
                unsigned short* __restrict__ dwout, float* __restrict__ biasm,
                float* __restrict__ sc3, float* __restrict__ bi3)
{
    __shared__ float shbuf[PH*64];                   // P3: plane[62][64]; P2: lds[64][57]
    int bid = blockIdx.x;
    int t = threadIdx.x;

    if (bid < 4096) {
        // ---------------- P3: depthwise 7x7, c = bid&255, b = bid>>8 ----------------
        float (*plane)[64] = (float(*)[64])shbuf;
        int c = bid & 255, b = bid >> 8;
#pragma unroll
        for (int j = 0; j < 4; ++j) {
            int idx = j*256 + t;
            if (idx < 992) ((f32x4*)plane)[idx] = (f32x4){0.f,0.f,0.f,0.f};
        }
        __syncthreads();
        const float* xp = x + ((size_t)b*DIM + c)*HWP;
#pragma unroll
        for (int j = 0; j < 13; ++j) {
            int idx = j*256 + t;
            if (idx < HWP) {
                int h = idx / 56, w = idx % 56;
                plane[h + 3][w + 3] = xp[idx];
            }
        }
        float wr[49];
#pragma unroll
        for (int i = 0; i < 49; ++i) wr[i] = dw7[c*49 + i] + dwk[c*49 + i];  // uniform -> SGPR
        __syncthreads();
        unsigned short* op = dwout + ((size_t)b*DIM + c)*HWP;
#pragma unroll
        for (int j = 0; j < 2; ++j) {                // 392 octs = 56 rows x 7
            int q = j*256 + t;
            if (q < 392) {
                int h = q / 7, w0 = (q % 7)*8;
                float a[8] = {0.f,0.f,0.f,0.f,0.f,0.f,0.f,0.f};
#pragma unroll
                for (int dy = 0; dy < 7; ++dy) {
                    const float* row = &plane[h + dy][w0];
                    union { f32x4 v[4]; float s[16]; } rr;
                    rr.v[0] = *(const f32x4*)(row);
                    rr.v[1] = *(const f32x4*)(row + 4);
                    rr.v[2] = *(const f32x4*)(row + 8);
                    rr.v[3] = *(const f32x4*)(row + 12);
#pragma unroll
                    for (int dx = 0; dx < 7; ++dx) {
                        float wv = wr[dy*7 + dx];
#pragma unroll
                        for (int o = 0; o < 8; ++o) a[o] += rr.s[dx + o] * wv;
                    }
                }
                uint4 pk;
                pk.x = (unsigned)f2bf(a[0]) | ((unsigned)f2bf(a[1]) << 16);
                pk.y = (unsigned)f2bf(a[2]) | ((unsigned)f2bf(a[3]) << 16);
                pk.z = (unsigned)f2bf(a[4]) | ((unsigned)f2bf(a[5]) << 16);
                pk.w = (unsigned)f2bf(a[6]) | ((unsigned)f2bf(a[7]) << 16);
                *(uint4*)&op[h*WW + w0] = pk;
            }
        }
        return;
    }

    if (bid < 8064) {
        // ---------------- P2: xpad, idx -> (cc, ph, b) ----------------
        float (*lds)[57] = (float(*)[57])shbuf;
        int idx0 = bid - 4096;
        int cc = idx0 & 3;                           // channel chunk of 64
        int r62 = (idx0 >> 2);
        int ph = r62 % PH, b = r62 / PH;
        int c0 = cc*64;
        char* rowc = (char*)xpad + ((size_t)(b*PH + ph)*PW)*(DIM*2) + c0*2;

        if (ph < 3 || ph >= HH + 3) {
            uint4 z = {0u,0u,0u,0u};
#pragma unroll
            for (int j = 0; j < 2; ++j) {
                int idx = j*256 + t;
                if (idx < 496) {
                    int pix = idx >> 3, q = idx & 7;
                    *(uint4*)(rowc + (size_t)pix*(DIM*2) + q*16) = z;
                }
            }
            return;
        }
        if (t < 48) {
            int p = t >> 3, q = t & 7;
            int pw = (p < 3) ? p : (PW - 6 + p);     // 0,1,2, 59,60,61
            uint4 z = {0u,0u,0u,0u};
            *(uint4*)(rowc + (size_t)pw*(DIM*2) + q*16) = z;
        }
        int h = ph - 3;
#pragma unroll
        for (int j = 0; j < 14; ++j) {               // 64*56 = 3584 = 14*256
            int idx = j*256 + t;
            int c = idx / 56, w = idx % 56;
            lds[c][w] = x[((size_t)(b*DIM + c0 + c)*HH + h)*WW + w];
        }
        __syncthreads();
#pragma unroll
        for (int j = 0; j < 7; ++j) {                // 56*32 pairs = 1792 = 7*256
            int idx = j*256 + t;
            int w = idx >> 5, cp = idx & 31;
            unsigned lo = f2bf(lds[2*cp][w]);
            unsigned hi = f2bf(lds[2*cp+1][w]);
            unsigned val = lo | (hi << 16);
            *(unsigned*)(rowc + (size_t)(w + 3)*(DIM*2) + 4*cp) = val;
        }
        return;
    }

    // ---------------- P1: weights, co = bid - 8064, t = ci ----------------
    {
        int co = bid - 8064;
        float s1 = g1[co] * rsqrtf(v1[co] + EPSV);
        float s2 = g2[co] * rsqrtf(v2[co] + EPSV);
        float w1v = w1[co*DIM + t] * s2;
        const float* w3r = w3 + (size_t)(co*DIM + t)*9;
#pragma unroll
        for (int s = 0; s < 9; ++s) {
            float v = w3r[s]*s1 + (s == 4 ? w1v : 0.f);
            WkT[((size_t)s*DIM + co)*DIM + t] = f2bf(v);   // layout [tap][co][ci]
        }
        if (t == 0) {
            biasm[co] = (b1[co] - m1[co]*s1) + (b2[co] - m2[co]*s2);
            float s3 = g3[co] * rsqrtf(v3[co] + EPSV);
            sc3[co] = s3;
            bi3[co] = b3[co] - m3[co]*s3;
        }
    }
}

// ---------------- Main: implicit-GEMM conv3x3, 128x128 tile, single-buffer 4 blocks/CU -
// R12-validated addressing/swizzle/tap-inner order. Structure change: NO double buffer
// (LDS 32KB) -> 4 blocks/CU -> all 784 blocks resident in ONE round (no ragged tail),
// and each block's stage-drain is covered by the other 3 blocks' compute (m114 cross-
// wave overlap) instead of an in-block software pipeline.
__global__ __launch_bounds__(256, 4)
void main_conv(const unsigned short* __restrict__ xpad, const unsigned short* __restrict__ WkT,
               const unsigned short* __restrict__ dwo, const float* __restrict__ biasm,
               const float* __restrict__ sc3, const float* __restrict__ bi3,
               float* __restrict__ out)
{
    __shared__ __align__(16) char smem[32768];       // single buf: A 16K + B 16K
    int t = threadIdx.x;
    int lane = t & 63, wv = t >> 6;
    int wm = wv >> 1, wn = wv & 1;
    int qm = lane & 15, qg = lane >> 4;
    int bx = blockIdx.y;                              // pixel tile (392)
    int byc = blockIdx.x;                             // co tile (2)

    int swz = (((lane & 7) ^ ((lane >> 3) & 7)) << 4);

    uintptr_t gA[4], gB[4];
#pragma unroll
    for (int r = 0; r < 4; ++r) {
        int pixt = r*32 + wv*8 + (lane >> 3);
        int P = bx*128 + pixt;
        int bb = P / HWP, rem = P % HWP;
        int h = rem / WW, w = rem % WW;
        gA[r] = (uintptr_t)xpad + ((size_t)((bb*PH + h + 2)*PW + (w + 2))*DIM)*2 + swz;
        int cog = byc*128 + pixt;
        gB[r] = (uintptr_t)WkT + ((size_t)cog*DIM)*2 + swz;
    }

    f32x4 acc[4][4] = {};

    auto stage = [&](int s) {
        int ch = s / 9, tap = s - ch*9;               // TAP-INNER, CHANNEL-OUTER
        int ky = tap / 3, kx = tap - ky*3;
        int offA = (ky*PW + kx)*(DIM*2) + ch*128;
        int offB = tap*(DIM*DIM*2) + ch*128;
#pragma unroll
        for (int r = 0; r < 4; ++r) {
            __builtin_amdgcn_global_load_lds(
                (const __attribute__((address_space(1))) void*)(gA[r] + offA),
                (__attribute__((address_space(3))) void*)(smem + (r*32 + wv*8)*128),
                16, 0, 0);
            __builtin_amdgcn_global_load_lds(
                (const __attribute__((address_space(1))) void*)(gB[r] + offB),
                (__attribute__((address_space(3))) void*)(smem + 16384 + (r*32 + wv*8)*128),
                16, 0, 0);
        }
    };

    int kxo = (qg << 4) ^ ((lane & 7) << 4);
    auto compute = [&]() {
        const char* pA = smem + (wm*64 + qm)*128;
        const char* pB = smem + 16384 + (wn*64 + qm)*128;
#pragma unroll
        for (int kk = 0; kk < 2; ++kk) {
            int ko = kxo ^ (kk << 6);
            bf16x8 a[4], b[4];
#pragma unroll
            for (int i = 0; i < 4; ++i) {
                a[i] = *(const bf16x8*)(pA + i*2048 + ko);
                b[i] = *(const bf16x8*)(pB + i*2048 + ko);
            }
#pragma unroll
            for (int i = 0; i < 4; ++i)
#pragma unroll
                for (int j = 0; j < 4; ++j)
                    acc[i][j] = __builtin_amdgcn_mfma_f32_16x16x32_bf16(a[i], b[j], acc[i][j], 0, 0, 0);
        }
    };

#define VMW0() asm volatile("s_waitcnt vmcnt(0)" ::: "memory")
#define BARX() { asm volatile("" ::: "memory"); __builtin_amdgcn_s_barrier(); asm volatile("" ::: "memory"); }

#pragma unroll 1
    for (int s = 0; s < 36; ++s) {
        stage(s);                         // issue this step's 8 loads
        VMW0(); BARX();                   // data landed & published (other blocks fill)
        compute();
        BARX();                           // all waves done reading before next overwrite
    }
#undef VMW0
#undef BARX

    // ---- epilogue: per-wave transpose through LDS -> coalesced NCHW stores ----
    float* ep = (float*)smem + wv*1088;               // 64 co x 16 pix, stride 17
#pragma unroll
    for (int mi = 0; mi < 4; ++mi) {
#pragma unroll
        for (int ni = 0; ni < 4; ++ni)
#pragma unroll
            for (int r = 0; r < 4; ++r)
                ep[(ni*16 + qm)*17 + 4*qg + r] = acc[mi][ni][r];
        __syncthreads();
        int P = bx*128 + wm*64 + mi*16 + qm;          // this lane's pixel
        int bb = P / HWP, rem = P % HWP;
        size_t obase = (size_t)bb*DIM*HWP + rem;
#pragma unroll
        for (int j = 0; j < 16; ++j) {
            int col = j*4 + qg;                       // 0..63 within wave's co range
            int cog = byc*128 + wn*64 + col;
            float z = ep[col*17 + qm] + biasm[cog];
            float rep = silu_f(z);
            float y = rep + bf2f(dwo[obase + (size_t)cog*HWP]);
            float yy = y * sc3[cog] + bi3[cog];
            out[obase + (size_t)cog*HWP] = silu_f(yy);
        }
        __syncthreads();
    }
}

// ---------------- launch ----------------
extern "C" void kernel_launch(void* const* d_in, const int* in_sizes, int n_in,
                              void* d_out, int out_size, void* d_ws, size_t ws_size,
                              hipStream_t stream)
{
    (void)in_sizes; (void)n_in; (void)out_size; (void)ws_size;
    const float* x   = (const float*)d_in[0];
    const float* w3  = (const float*)d_in[1];
    const float* g1  = (const float*)d_in[2];
    const float* b1  = (const float*)d_in[3];
    const float* m1  = (const float*)d_in[4];
    const float* v1  = (const float*)d_in[5];
    const float* w1  = (const float*)d_in[6];
    const float* g2  = (const float*)d_in[7];
    const float* b2  = (const float*)d_in[8];
    const float* m2  = (const float*)d_in[9];
    const float* v2  = (const float*)d_in[10];
    const float* dw7 = (const float*)d_in[11];
    const float* dwk = (const float*)d_in[12];
    const float* g3  = (const float*)d_in[13];
    const float* b3  = (const float*)d_in[14];
    const float* m3  = (const float*)d_in[15];
    const float* v3  = (const float*)d_in[16];
    float* out = (float*)d_out;

    char* ws = (char*)d_ws;
    unsigned short* xpad = (unsigned short*)(ws);                 // 16*62*62*256*2 = 31,490,048
    unsigned short* WkT  = (unsigned short*)(ws + 31490048);      // 9*256*256*2    =  1,179,648
    unsigned short* dwo  = (unsigned short*)(ws + 32669696);      // 16*256*3136*2  = 25,690,112
    float* biasm = (float*)(ws + 58359808);
    float* sc3   = (float*)(ws + 58360832);
    float* bi3   = (float*)(ws + 58361856);                       // end ~58.4 MB

    fused_prep<<<dim3(8320), dim3(256), 0, stream>>>(
        x, w3, g1, b1, m1, v1, w1, g2, b2, m2, v2, dw7, dwk, g3, b3, m3, v3,
        xpad, WkT, dwo, biasm, sc3, bi3);
    main_conv<<<dim3(2, NPIX/128), dim3(256), 0, stream>>>(xpad, WkT, dwo, biasm, sc3, bi3, out);
}